// Round 1
// baseline (12.561 us; speedup 1.0000x reference)
//
#include <hip/hip_runtime.h>

// DEQ solver with elementwise ISTA map: the fixed point is closed-form,
//   z* = sign(x0) * max(|x0| - lam, 0)
// and the returned ista_step(z*, x0) == z*. So the entire Anderson solve
// reduces to one soft-threshold pass over x0. Memory-bound: ~50 MB traffic.

__global__ void __launch_bounds__(256)
deq_softthresh_kernel(const float4* __restrict__ x4,
                      const float* __restrict__ lam_p,
                      float4* __restrict__ out4,
                      int n4) {
    const float lam = lam_p[0];  // scalar, L2/L1-cached broadcast
    int idx = blockIdx.x * blockDim.x + threadIdx.x;
    const int stride = gridDim.x * blockDim.x;
    for (; idx < n4; idx += stride) {
        float4 v = x4[idx];
        float4 r;
        // soft-threshold each component: sign(x)*max(|x|-lam, 0)
        {
            float a = fabsf(v.x) - lam;
            r.x = copysignf(fmaxf(a, 0.0f), v.x);
        }
        {
            float a = fabsf(v.y) - lam;
            r.y = copysignf(fmaxf(a, 0.0f), v.y);
        }
        {
            float a = fabsf(v.z) - lam;
            r.z = copysignf(fmaxf(a, 0.0f), v.z);
        }
        {
            float a = fabsf(v.w) - lam;
            r.w = copysignf(fmaxf(a, 0.0f), v.w);
        }
        out4[idx] = r;
    }
}

extern "C" void kernel_launch(void* const* d_in, const int* in_sizes, int n_in,
                              void* d_out, int out_size, void* d_ws, size_t ws_size,
                              hipStream_t stream) {
    const float* x0  = (const float*)d_in[0];   // (8,3,512,512) fp32
    // d_in[1] = rho (unused: cancels out of the fixed point)
    const float* lam = (const float*)d_in[2];   // scalar fp32
    float* out = (float*)d_out;

    const int n  = in_sizes[0];      // 6291456, divisible by 4
    const int n4 = n >> 2;           // 1572864 float4 elements

    const int block = 256;
    int grid = (n4 + block - 1) / block;
    if (grid > 2048) grid = 2048;    // grid-stride beyond this

    deq_softthresh_kernel<<<grid, block, 0, stream>>>(
        (const float4*)x0, lam, (float4*)out, n4);
}

// Round 3
// 10.373 us; speedup vs baseline: 1.2110x; 1.2110x over previous
//
#include <hip/hip_runtime.h>

// DEQ solver, closed-form: out = sign(x0) * max(|x0| - lam, 0).
// Pure streaming, 50.3 MB traffic. Specialized path: 2048 blocks x 256
// threads x 3 float4/thread (exact for n=6291456), loads issued
// back-to-back for MLP, non-temporal stores.
// Use clang native vector type: __builtin_nontemporal_store rejects
// HIP_vector_type<float,4>.

typedef float f32x4 __attribute__((ext_vector_type(4)));

__device__ __forceinline__ f32x4 soft4(f32x4 v, float lam) {
    f32x4 r;
    r.x = copysignf(fmaxf(fabsf(v.x) - lam, 0.0f), v.x);
    r.y = copysignf(fmaxf(fabsf(v.y) - lam, 0.0f), v.y);
    r.z = copysignf(fmaxf(fabsf(v.z) - lam, 0.0f), v.z);
    r.w = copysignf(fmaxf(fabsf(v.w) - lam, 0.0f), v.w);
    return r;
}

__global__ void __launch_bounds__(256)
deq_soft3_kernel(const f32x4* __restrict__ x4,
                 const float* __restrict__ lam_p,
                 f32x4* __restrict__ out4) {
    const float lam = lam_p[0];
    const int tid = blockIdx.x * 256 + threadIdx.x;
    const int stride = 2048 * 256;

    // three independent loads in flight
    f32x4 v0 = x4[tid];
    f32x4 v1 = x4[tid + stride];
    f32x4 v2 = x4[tid + 2 * stride];

    f32x4 r0 = soft4(v0, lam);
    f32x4 r1 = soft4(v1, lam);
    f32x4 r2 = soft4(v2, lam);

    __builtin_nontemporal_store(r0, &out4[tid]);
    __builtin_nontemporal_store(r1, &out4[tid + stride]);
    __builtin_nontemporal_store(r2, &out4[tid + 2 * stride]);
}

__global__ void __launch_bounds__(256)
deq_soft_fallback(const f32x4* __restrict__ x4,
                  const float* __restrict__ lam_p,
                  f32x4* __restrict__ out4, int n4) {
    const float lam = lam_p[0];
    int idx = blockIdx.x * blockDim.x + threadIdx.x;
    const int stride = gridDim.x * blockDim.x;
    for (; idx < n4; idx += stride)
        out4[idx] = soft4(x4[idx], lam);
}

extern "C" void kernel_launch(void* const* d_in, const int* in_sizes, int n_in,
                              void* d_out, int out_size, void* d_ws, size_t ws_size,
                              hipStream_t stream) {
    const float* x0  = (const float*)d_in[0];   // (8,3,512,512) fp32
    const float* lam = (const float*)d_in[2];   // scalar fp32
    float* out = (float*)d_out;

    const int n  = in_sizes[0];
    const int n4 = n >> 2;

    if (n4 == 2048 * 256 * 3) {
        deq_soft3_kernel<<<2048, 256, 0, stream>>>(
            (const f32x4*)x0, lam, (f32x4*)out);
    } else {
        const int block = 256;
        int grid = (n4 + block - 1) / block;
        if (grid > 2048) grid = 2048;
        deq_soft_fallback<<<grid, block, 0, stream>>>(
            (const f32x4*)x0, lam, (f32x4*)out, n4);
    }
}